// Round 10
// baseline (247.290 us; speedup 1.0000x reference)
//
#include <hip/hip_runtime.h>
#include <cstdint>
#include <cstddef>

// Problem constants
#define B_ 8
#define C_ 512
#define L_ 4096
#define M_ 2048   // L/2 (pooled keys)
#define CK_ 64    // C/8
#define CV_ 256   // C/2

typedef _Float16 f16;
typedef _Float16 f16x8 __attribute__((ext_vector_type(8)));
typedef _Float16 f16x4 __attribute__((ext_vector_type(4)));
typedef float f32x4 __attribute__((ext_vector_type(4)));
typedef float f32x16 __attribute__((ext_vector_type(16)));
typedef unsigned int u32x4 __attribute__((ext_vector_type(4)));

#define MFMA16(A, Bv, Cv) __builtin_amdgcn_mfma_f32_16x16x32_f16(A, Bv, Cv, 0, 0, 0)
#define MFMA32(A, Bv, Cv) __builtin_amdgcn_mfma_f32_32x32x16_f16(A, Bv, Cv, 0, 0, 0)

#define LOG2E 1.44269504f

static __device__ __forceinline__ uint32_t pkrtz(float a, float b) {
    return __builtin_bit_cast(uint32_t, __builtin_amdgcn_cvt_pkrtz(a, b));
}

// ---------------------------------------------------------------------------
// Kernel W: all weight conversions in one launch.
// ---------------------------------------------------------------------------
__global__ __launch_bounds__(256) void cvt_all(const float* __restrict__ Wt,
                                               const float* __restrict__ Wp,
                                               const float* __restrict__ Wg,
                                               const float* __restrict__ Wo,
                                               f16* __restrict__ Wall,
                                               f16* __restrict__ Wo_h) {
    const int i = blockIdx.x * 256 + threadIdx.x;
    const int NT = CK_ * C_;          // 32768
    const int NG = CV_ * C_;          // 131072
    if (i < NT) Wall[i] = (f16)Wt[i];
    else if (i < 2 * NT) Wall[i] = (f16)Wp[i - NT];
    else if (i < 2 * NT + NG) Wall[i] = (f16)Wg[i - 2 * NT];
    else Wo_h[i - 2 * NT - NG] = (f16)Wo[i - 2 * NT - NG];
}

// ---------------------------------------------------------------------------
// Fused projection kernel (MFMA f16, fp32 accum), x staged via LDS.
//   (unchanged from round 8 — verified)
// ---------------------------------------------------------------------------
__global__ __launch_bounds__(256) void fused_proj(const f16* __restrict__ Wall,
                                                  const float* __restrict__ x,
                                                  f16* __restrict__ theta2,
                                                  f16* __restrict__ phi2,
                                                  f16* __restrict__ g2) {
    __shared__ __align__(16) f16 xs[64][32][8];  // 32 KB
    const int b    = blockIdx.y;
    const int l0   = blockIdx.x * 32;
    const int tid  = threadIdx.x;
    const int w    = tid >> 6;           // warp: och range [w*96, w*96+96)
    const int lane = tid & 63;
    const int lq   = lane & 15;
    const int g    = lane >> 4;
    const int wb   = w * 96;

    // ---- stage x tile -> LDS (f16, fragment-native) ----
    {
        const float* xb = x + (size_t)b * C_ * L_ + l0 + (tid & 31);
        const int co0 = tid >> 5;  // 0..7
#pragma unroll
        for (int i = 0; i < 8; ++i) {
            const int co = i * 8 + co0;
            float v[8];
#pragma unroll
            for (int j = 0; j < 8; ++j) v[j] = xb[(size_t)(co * 8 + j) * L_];
            u32x4 p = {pkrtz(v[0], v[1]), pkrtz(v[2], v[3]),
                       pkrtz(v[4], v[5]), pkrtz(v[6], v[7])};
            *reinterpret_cast<u32x4*>(&xs[co][tid & 31][0]) = p;
        }
    }
    __syncthreads();

    f32x4 acc[6][2] = {};
    for (int ks = 0; ks < 16; ++ks) {
        const int c0 = ks * 32;
        f16x8 Bf[2];
#pragma unroll
        for (int lt = 0; lt < 2; ++lt)
            Bf[lt] = *reinterpret_cast<const f16x8*>(&xs[ks * 4 + g][lt * 16 + lq][0]);
#pragma unroll
        for (int t = 0; t < 6; ++t) {
            f16x8 Af = *reinterpret_cast<const f16x8*>(
                Wall + (size_t)(wb + t * 16 + lq) * C_ + c0 + 8 * g);
            acc[t][0] = MFMA16(Af, Bf[0], acc[t][0]);
            acc[t][1] = MFMA16(Af, Bf[1], acc[t][1]);
        }
    }

    // Epilogue. D layout (MFMA16): row = 4g + r (och), col = lq (l).
#pragma unroll
    for (int t = 0; t < 6; ++t) {
        const int och0 = wb + t * 16;
#pragma unroll
        for (int lt = 0; lt < 2; ++lt) {
            const int l = l0 + lt * 16 + lq;
            if (och0 < 64) {
#pragma unroll
                for (int r = 0; r < 4; ++r) {
                    const int och = och0 + 4 * g + r;
                    theta2[(((size_t)b * 8 + (och >> 3)) * L_ + l) * 8 + (och & 7)] =
                        (f16)(acc[t][lt][r] * LOG2E);
                }
            } else {
#pragma unroll
                for (int r = 0; r < 4; ++r) {
                    const float pv = fmaxf(acc[t][lt][r], __shfl_xor(acc[t][lt][r], 1));
                    if (!(lane & 1)) {
                        const int m = l >> 1;
                        if (och0 < 128) {
                            const int kc = och0 - 64 + 4 * g + r;
                            phi2[(((size_t)b * 8 + (kc >> 3)) * M_ + m) * 8 + (kc & 7)] =
                                (f16)pv;
                        } else {
                            const int vc = och0 - 128 + 4 * g + r;
                            g2[(((size_t)b * 256 + (m >> 3)) * CV_ + vc) * 8 + (m & 7)] =
                                (f16)pv;
                        }
                    }
                }
            }
        }
    }
}

// ---------------------------------------------------------------------------
// Kernel B: flash attention, zero LDS / zero barriers.
//   EXACT round-8 version (verified pass + post-timing stable). Round 9's
//   K-prefetch unroll caused post-timing divergence and no speedup — the
//   kernel is dependency-chain-bound, not K-load-latency-bound.
// ---------------------------------------------------------------------------
__global__ __launch_bounds__(512, 4) void attn_flash(const f16* __restrict__ theta2,
                                                     const f16* __restrict__ phi2,
                                                     const f16* __restrict__ g2,
                                                     f16* __restrict__ o_inT) {
    const int bid = blockIdx.x;
    const int b   = bid & 7;            // XCD-major: one batch per XCD
    const int qt  = bid >> 3;           // 64 q-tiles (of 64) per batch
    const int w   = threadIdx.x >> 6;   // 0..7
    const int qg  = w >> 2;             // 0..1
    const int vq  = w & 3;              // 0..3
    const int q0  = qt * 64 + qg * 32;
    const int vb  = vq * 64;
    const int lane = threadIdx.x & 63;
    const int lq   = lane & 31;
    const int hi   = lane >> 5;

    const f16* qbase = theta2 + (size_t)b * 8 * L_ * 8;
    f16x8 Qf[4];
#pragma unroll
    for (int f = 0; f < 4; ++f)
        Qf[f] = *reinterpret_cast<const f16x8*>(
            qbase + ((size_t)(2 * f + hi) * L_ + q0 + lq) * 8);

    f32x16 acc[2] = {};
    float m_run = -3.0e38f;
    float l_run = 0.f;

    const f16* kbase = phi2 + (size_t)b * 8 * M_ * 8;
    const f16* vbase = g2 + (size_t)b * 256 * CV_ * 8;

    for (int m0 = 0; m0 < M_; m0 += 32) {
        // ---- loads (coalesced; K identical across all 8 warps -> L1) ----
        f16x8 Kf[4];
#pragma unroll
        for (int f = 0; f < 4; ++f)
            Kf[f] = *reinterpret_cast<const f16x8*>(
                kbase + ((size_t)(2 * f + hi) * M_ + m0 + lq) * 8);
        f16x8 Vf[2][2];
#pragma unroll
        for (int ch = 0; ch < 2; ++ch)
#pragma unroll
            for (int vt = 0; vt < 2; ++vt)
                Vf[ch][vt] = *reinterpret_cast<const f16x8*>(
                    vbase + ((size_t)((m0 >> 3) + 2 * ch + hi) * CV_ +
                             vb + vt * 32 + lq) * 8);

        // ---- QK^T (scores in log2 units): S^T[m][q], col = q ----
        f32x16 S = {};
        __builtin_amdgcn_s_setprio(1);
#pragma unroll
        for (int f = 0; f < 4; ++f) S = MFMA32(Kf[f], Qf[f], S);
        __builtin_amdgcn_s_setprio(0);

        // ---- online softmax, exp2 domain (per-lane; q is lane-local) ----
        float t0 = fmaxf(fmaxf(S[0], S[1]), S[2]);
        float t1 = fmaxf(fmaxf(S[3], S[4]), S[5]);
        float t2 = fmaxf(fmaxf(S[6], S[7]), S[8]);
        float t3 = fmaxf(fmaxf(S[9], S[10]), S[11]);
        float t4 = fmaxf(fmaxf(S[12], S[13]), S[14]);
        float tm = fmaxf(fmaxf(fmaxf(t0, t1), t2),
                         fmaxf(fmaxf(t3, t4), S[15]));
        tm = fmaxf(tm, __shfl_xor(tm, 32));
        if (tm > m_run + 11.5f) {  // defer-max (11.5 log2 units ~= 8 nats)
            float sc = __builtin_amdgcn_exp2f(m_run - tm);
#pragma unroll
            for (int vt = 0; vt < 2; ++vt)
#pragma unroll
                for (int r = 0; r < 16; ++r) acc[vt][r] *= sc;
            l_run *= sc;
            m_run = tm;
        }
        float s[16];
#pragma unroll
        for (int r = 0; r < 16; ++r) s[r] = __builtin_amdgcn_exp2f(S[r] - m_run);
        float a0 = (s[0] + s[1]) + (s[2] + s[3]);
        float a1 = (s[4] + s[5]) + (s[6] + s[7]);
        float a2 = (s[8] + s[9]) + (s[10] + s[11]);
        float a3 = (s[12] + s[13]) + (s[14] + s[15]);
        float ls = (a0 + a1) + (a2 + a3);
        l_run += ls + __shfl_xor(ls, 32);

        // ---- P -> f16 B-fragments (cvt_pkrtz + permlane32_swap, T12) ----
        uint32_t pk[8];
#pragma unroll
        for (int i = 0; i < 8; ++i) pk[i] = pkrtz(s[2 * i], s[2 * i + 1]);
        asm volatile("v_permlane32_swap_b32 %0, %1" : "+v"(pk[0]), "+v"(pk[2]));
        asm volatile("v_permlane32_swap_b32 %0, %1" : "+v"(pk[1]), "+v"(pk[3]));
        asm volatile("v_permlane32_swap_b32 %0, %1" : "+v"(pk[4]), "+v"(pk[6]));
        asm volatile("v_permlane32_swap_b32 %0, %1" : "+v"(pk[5]), "+v"(pk[7]));
        u32x4 fr0 = {pk[0], pk[1], pk[2], pk[3]};
        u32x4 fr1 = {pk[4], pk[5], pk[6], pk[7]};
        f16x8 P0 = __builtin_bit_cast(f16x8, fr0);
        f16x8 P1 = __builtin_bit_cast(f16x8, fr1);

        // ---- PV ----
        __builtin_amdgcn_s_setprio(1);
#pragma unroll
        for (int vt = 0; vt < 2; ++vt) acc[vt] = MFMA32(Vf[0][vt], P0, acc[vt]);
#pragma unroll
        for (int vt = 0; vt < 2; ++vt) acc[vt] = MFMA32(Vf[1][vt], P1, acc[vt]);
        __builtin_amdgcn_s_setprio(0);
    }

    // ---- epilogue: normalize, store o_inT[b][q][v] ----
    const float inv = 1.f / l_run;
    f16* op = o_inT + ((size_t)b * L_ + q0 + lq) * CV_ + vb + 4 * hi;
#pragma unroll
    for (int vt = 0; vt < 2; ++vt)
#pragma unroll
        for (int rq = 0; rq < 4; ++rq) {
            f16x4 o;
#pragma unroll
            for (int j = 0; j < 4; ++j) o[j] = (f16)(acc[vt][4 * rq + j] * inv);
            *reinterpret_cast<f16x4*>(op + vt * 32 + 8 * rq) = o;
        }
}

// ---------------------------------------------------------------------------
// Kernel C: MFMA output projection + residual.
//   Operand roles swapped vs round 8: mfma(o_in_frag, Wo_frag) puts l in
//   D-rows (row = 4g+r -> 4 consecutive l per thread, col = oc = lq), so
//   the epilogue does float4 x-loads and float4 out-stores (4x fewer VMEM
//   insts). Fragment loads themselves are unchanged.
// ---------------------------------------------------------------------------
__global__ __launch_bounds__(256) void out_mfma(const f16* __restrict__ Wo_h,
                                                const f16* __restrict__ o_inT,
                                                const float* __restrict__ x,
                                                const float* __restrict__ gamma_p,
                                                float* __restrict__ out) {
    const int b    = blockIdx.z;
    const int l0   = blockIdx.x * 64;
    const int wid  = threadIdx.x >> 6;
    const int oc0  = blockIdx.y * 64 + wid * 16;
    const int lane = threadIdx.x & 63;
    const int lq   = lane & 15;
    const int g    = lane >> 4;

    f32x4 acc[4] = {{0.f, 0.f, 0.f, 0.f}, {0.f, 0.f, 0.f, 0.f},
                    {0.f, 0.f, 0.f, 0.f}, {0.f, 0.f, 0.f, 0.f}};
    const f16* ap = Wo_h + (size_t)(oc0 + lq) * CV_;  // B-operand: col = oc
#pragma unroll
    for (int ks = 0; ks < 8; ++ks) {
        f16x8 Wf = *reinterpret_cast<const f16x8*>(ap + ks * 32 + 8 * g);
#pragma unroll
        for (int lt = 0; lt < 4; ++lt) {
            const f16* bp = o_inT + ((size_t)b * L_ + l0 + lt * 16 + lq) * CV_ + ks * 32 + 8 * g;
            acc[lt] = MFMA16(*reinterpret_cast<const f16x8*>(bp), Wf, acc[lt]);
        }
    }
    const float gamma = *gamma_p;
#pragma unroll
    for (int lt = 0; lt < 4; ++lt) {
        // D: row = l-in-tile = 4g + r, col = oc = oc0 + lq
        const size_t o = ((size_t)b * C_ + oc0 + lq) * L_ + l0 + lt * 16 + 4 * g;
        float4 xv = *reinterpret_cast<const float4*>(x + o);
        float4 ov;
        ov.x = fmaf(gamma, acc[lt][0], xv.x);
        ov.y = fmaf(gamma, acc[lt][1], xv.y);
        ov.z = fmaf(gamma, acc[lt][2], xv.z);
        ov.w = fmaf(gamma, acc[lt][3], xv.w);
        *reinterpret_cast<float4*>(out + o) = ov;
    }
}

// ---------------------------------------------------------------------------
extern "C" void kernel_launch(void* const* d_in, const int* in_sizes, int n_in,
                              void* d_out, int out_size, void* d_ws, size_t ws_size,
                              hipStream_t stream) {
    const float* x       = (const float*)d_in[0];
    const float* W_theta = (const float*)d_in[1];
    const float* W_phi   = (const float*)d_in[2];
    const float* W_g     = (const float*)d_in[3];
    const float* W_o     = (const float*)d_in[4];
    const float* gamma   = (const float*)d_in[5];
    float* out = (float*)d_out;

    // workspace carve (f16): theta2 | phi2 | g2 | o_inT | Wo_h | Wall
    f16* theta2 = (f16*)d_ws;                          // [B][8][L][8]
    f16* phi2   = theta2 + (size_t)B_ * 8 * L_ * 8;    // [B][8][M][8]
    f16* g2     = phi2 + (size_t)B_ * 8 * M_ * 8;      // [B][256][CV][8]
    f16* o_inT  = g2 + (size_t)B_ * 256 * CV_ * 8;     // [B][L][CV]
    f16* Wo_h   = o_inT + (size_t)B_ * L_ * CV_;       // [C][CV]
    f16* Wall   = Wo_h + (size_t)C_ * CV_;             // [384][C]

    const int cvt_n = 2 * CK_ * C_ + CV_ * C_ + C_ * CV_;  // 327680
    cvt_all<<<dim3(cvt_n / 256), 256, 0, stream>>>(W_theta, W_phi, W_g, W_o, Wall, Wo_h);
    fused_proj<<<dim3(L_ / 32, B_), 256, 0, stream>>>(Wall, x, theta2, phi2, g2);
    attn_flash<<<dim3(512), 512, 0, stream>>>(theta2, phi2, g2, o_inT);
    out_mfma<<<dim3(L_ / 64, C_ / 64, B_), 256, 0, stream>>>(Wo_h, o_inT, x, gamma, out);
}

// Round 11
// 177.301 us; speedup vs baseline: 1.3947x; 1.3947x over previous
//
#include <hip/hip_runtime.h>
#include <cstdint>
#include <cstddef>

// Problem constants
#define B_ 8
#define C_ 512
#define L_ 4096
#define M_ 2048   // L/2 (pooled keys)
#define CK_ 64    // C/8
#define CV_ 256   // C/2

typedef _Float16 f16;
typedef _Float16 f16x8 __attribute__((ext_vector_type(8)));
typedef _Float16 f16x4 __attribute__((ext_vector_type(4)));
typedef float f32x4 __attribute__((ext_vector_type(4)));
typedef float f32x16 __attribute__((ext_vector_type(16)));
typedef unsigned int u32x4 __attribute__((ext_vector_type(4)));

#define MFMA16(A, Bv, Cv) __builtin_amdgcn_mfma_f32_16x16x32_f16(A, Bv, Cv, 0, 0, 0)
#define MFMA32(A, Bv, Cv) __builtin_amdgcn_mfma_f32_32x32x16_f16(A, Bv, Cv, 0, 0, 0)

#define LOG2E 1.44269504f

static __device__ __forceinline__ uint32_t pkrtz(float a, float b) {
    return __builtin_bit_cast(uint32_t, __builtin_amdgcn_cvt_pkrtz(a, b));
}

// ---------------------------------------------------------------------------
// Kernel W: weight conversion into FRAGMENT-NATIVE layouts.
//   WallF[tile=och>>4][ks=c>>5][lane=g*16+(och&15)][elem=c&7], g=(c>>3)&3
//     (tiles: 0-3 Wt, 4-7 Wp, 8-23 Wg; 24*16*64*8 = 196608 f16)
//   WoF[tile=oc>>4][ks=v>>5][lane=g*16+(oc&15)][elem=v&7]
//     (32*8*64*8 = 131072 f16)
//   Reads coalesced; scattered 2B writes are fine (runs once, 0.6 MB).
// ---------------------------------------------------------------------------
__global__ __launch_bounds__(256) void cvt_all(const float* __restrict__ Wt,
                                               const float* __restrict__ Wp,
                                               const float* __restrict__ Wg,
                                               const float* __restrict__ Wo,
                                               f16* __restrict__ WallF,
                                               f16* __restrict__ WoF) {
    const int i = blockIdx.x * 256 + threadIdx.x;
    const int NW = 384 * 512;  // 196608
    if (i < NW) {
        const int och = i >> 9, c = i & 511;
        float v;
        if (och < 64)       v = Wt[i];
        else if (och < 128) v = Wp[i - 64 * 512];
        else                v = Wg[i - 128 * 512];
        const int idx = (((och >> 4) * 16 + (c >> 5)) * 64 +
                         (((c >> 3) & 3) << 4) + (och & 15)) * 8 + (c & 7);
        WallF[idx] = (f16)v;
    } else {
        const int j = i - NW;  // < 131072
        const int oc = j >> 8, v = j & 255;
        const int idx = (((oc >> 4) * 8 + (v >> 5)) * 64 +
                         (((v >> 3) & 3) << 4) + (oc & 15)) * 8 + (v & 7);
        WoF[idx] = (f16)Wo[j];
    }
}

// ---------------------------------------------------------------------------
// Fused projection kernel (MFMA f16, fp32 accum), x staged via LDS.
//   A-frags now from WallF: one 1KB-contiguous wave-load each (was 64
//   distinct 64B lines at 1KB lane-stride). Rest identical to r8-verified.
// ---------------------------------------------------------------------------
__global__ __launch_bounds__(256) void fused_proj(const f16* __restrict__ WallF,
                                                  const float* __restrict__ x,
                                                  f16* __restrict__ theta2,
                                                  f16* __restrict__ phi2,
                                                  f16* __restrict__ g2) {
    __shared__ __align__(16) f16 xs[64][32][8];  // 32 KB
    const int b    = blockIdx.y;
    const int l0   = blockIdx.x * 32;
    const int tid  = threadIdx.x;
    const int w    = tid >> 6;           // warp: och range [w*96, w*96+96)
    const int lane = tid & 63;
    const int lq   = lane & 15;
    const int g    = lane >> 4;
    const int wb   = w * 96;

    // ---- stage x tile -> LDS (f16, fragment-native) ----
    {
        const float* xb = x + (size_t)b * C_ * L_ + l0 + (tid & 31);
        const int co0 = tid >> 5;  // 0..7
#pragma unroll
        for (int i = 0; i < 8; ++i) {
            const int co = i * 8 + co0;
            float v[8];
#pragma unroll
            for (int j = 0; j < 8; ++j) v[j] = xb[(size_t)(co * 8 + j) * L_];
            u32x4 p = {pkrtz(v[0], v[1]), pkrtz(v[2], v[3]),
                       pkrtz(v[4], v[5]), pkrtz(v[6], v[7])};
            *reinterpret_cast<u32x4*>(&xs[co][tid & 31][0]) = p;
        }
    }
    __syncthreads();

    f32x4 acc[6][2] = {};
    for (int ks = 0; ks < 16; ++ks) {
        f16x8 Bf[2];
#pragma unroll
        for (int lt = 0; lt < 2; ++lt)
            Bf[lt] = *reinterpret_cast<const f16x8*>(&xs[ks * 4 + g][lt * 16 + lq][0]);
#pragma unroll
        for (int t = 0; t < 6; ++t) {
            // tile index = och>>4 = 6w + t
            f16x8 Af = *reinterpret_cast<const f16x8*>(
                WallF + (((size_t)(6 * w + t) * 16 + ks) * 64 + lane) * 8);
            acc[t][0] = MFMA16(Af, Bf[0], acc[t][0]);
            acc[t][1] = MFMA16(Af, Bf[1], acc[t][1]);
        }
    }

    // Epilogue. D layout (MFMA16): row = 4g + r (och), col = lq (l).
#pragma unroll
    for (int t = 0; t < 6; ++t) {
        const int och0 = wb + t * 16;
#pragma unroll
        for (int lt = 0; lt < 2; ++lt) {
            const int l = l0 + lt * 16 + lq;
            if (och0 < 64) {
#pragma unroll
                for (int r = 0; r < 4; ++r) {
                    const int och = och0 + 4 * g + r;
                    theta2[(((size_t)b * 8 + (och >> 3)) * L_ + l) * 8 + (och & 7)] =
                        (f16)(acc[t][lt][r] * LOG2E);
                }
            } else {
#pragma unroll
                for (int r = 0; r < 4; ++r) {
                    const float pv = fmaxf(acc[t][lt][r], __shfl_xor(acc[t][lt][r], 1));
                    if (!(lane & 1)) {
                        const int m = l >> 1;
                        if (och0 < 128) {
                            const int kc = och0 - 64 + 4 * g + r;
                            phi2[(((size_t)b * 8 + (kc >> 3)) * M_ + m) * 8 + (kc & 7)] =
                                (f16)pv;
                        } else {
                            const int vc = och0 - 128 + 4 * g + r;
                            g2[(((size_t)b * 256 + (m >> 3)) * CV_ + vc) * 8 + (m & 7)] =
                                (f16)pv;
                        }
                    }
                }
            }
        }
    }
}

// ---------------------------------------------------------------------------
// Kernel B: flash attention, zero LDS / zero barriers.
//   Loop body byte-identical to round-8 (verified pass + post-timing
//   stable). Epilogue re-addressed to write o2 in out_mfma's B-fragment
//   layout: o2[b][l>>4][v>>5][lane'=((v>>3)&3)*16+(l&15)][v&7].
// ---------------------------------------------------------------------------
__global__ __launch_bounds__(512, 4) void attn_flash(const f16* __restrict__ theta2,
                                                     const f16* __restrict__ phi2,
                                                     const f16* __restrict__ g2,
                                                     f16* __restrict__ o2) {
    const int bid = blockIdx.x;
    const int b   = bid & 7;            // XCD-major: one batch per XCD
    const int qt  = bid >> 3;           // 64 q-tiles (of 64) per batch
    const int w   = threadIdx.x >> 6;   // 0..7
    const int qg  = w >> 2;             // 0..1
    const int vq  = w & 3;              // 0..3
    const int q0  = qt * 64 + qg * 32;
    const int vb  = vq * 64;
    const int lane = threadIdx.x & 63;
    const int lq   = lane & 31;
    const int hi   = lane >> 5;

    const f16* qbase = theta2 + (size_t)b * 8 * L_ * 8;
    f16x8 Qf[4];
#pragma unroll
    for (int f = 0; f < 4; ++f)
        Qf[f] = *reinterpret_cast<const f16x8*>(
            qbase + ((size_t)(2 * f + hi) * L_ + q0 + lq) * 8);

    f32x16 acc[2] = {};
    float m_run = -3.0e38f;
    float l_run = 0.f;

    const f16* kbase = phi2 + (size_t)b * 8 * M_ * 8;
    const f16* vbase = g2 + (size_t)b * 256 * CV_ * 8;

    for (int m0 = 0; m0 < M_; m0 += 32) {
        // ---- loads (coalesced; K identical across all 8 warps -> L1) ----
        f16x8 Kf[4];
#pragma unroll
        for (int f = 0; f < 4; ++f)
            Kf[f] = *reinterpret_cast<const f16x8*>(
                kbase + ((size_t)(2 * f + hi) * M_ + m0 + lq) * 8);
        f16x8 Vf[2][2];
#pragma unroll
        for (int ch = 0; ch < 2; ++ch)
#pragma unroll
            for (int vt = 0; vt < 2; ++vt)
                Vf[ch][vt] = *reinterpret_cast<const f16x8*>(
                    vbase + ((size_t)((m0 >> 3) + 2 * ch + hi) * CV_ +
                             vb + vt * 32 + lq) * 8);

        // ---- QK^T (scores in log2 units): S^T[m][q], col = q ----
        f32x16 S = {};
        __builtin_amdgcn_s_setprio(1);
#pragma unroll
        for (int f = 0; f < 4; ++f) S = MFMA32(Kf[f], Qf[f], S);
        __builtin_amdgcn_s_setprio(0);

        // ---- online softmax, exp2 domain (per-lane; q is lane-local) ----
        float t0 = fmaxf(fmaxf(S[0], S[1]), S[2]);
        float t1 = fmaxf(fmaxf(S[3], S[4]), S[5]);
        float t2 = fmaxf(fmaxf(S[6], S[7]), S[8]);
        float t3 = fmaxf(fmaxf(S[9], S[10]), S[11]);
        float t4 = fmaxf(fmaxf(S[12], S[13]), S[14]);
        float tm = fmaxf(fmaxf(fmaxf(t0, t1), t2),
                         fmaxf(fmaxf(t3, t4), S[15]));
        tm = fmaxf(tm, __shfl_xor(tm, 32));
        if (tm > m_run + 11.5f) {  // defer-max (11.5 log2 units ~= 8 nats)
            float sc = __builtin_amdgcn_exp2f(m_run - tm);
#pragma unroll
            for (int vt = 0; vt < 2; ++vt)
#pragma unroll
                for (int r = 0; r < 16; ++r) acc[vt][r] *= sc;
            l_run *= sc;
            m_run = tm;
        }
        float s[16];
#pragma unroll
        for (int r = 0; r < 16; ++r) s[r] = __builtin_amdgcn_exp2f(S[r] - m_run);
        float a0 = (s[0] + s[1]) + (s[2] + s[3]);
        float a1 = (s[4] + s[5]) + (s[6] + s[7]);
        float a2 = (s[8] + s[9]) + (s[10] + s[11]);
        float a3 = (s[12] + s[13]) + (s[14] + s[15]);
        float ls = (a0 + a1) + (a2 + a3);
        l_run += ls + __shfl_xor(ls, 32);

        // ---- P -> f16 B-fragments (cvt_pkrtz + permlane32_swap, T12) ----
        uint32_t pk[8];
#pragma unroll
        for (int i = 0; i < 8; ++i) pk[i] = pkrtz(s[2 * i], s[2 * i + 1]);
        asm volatile("v_permlane32_swap_b32 %0, %1" : "+v"(pk[0]), "+v"(pk[2]));
        asm volatile("v_permlane32_swap_b32 %0, %1" : "+v"(pk[1]), "+v"(pk[3]));
        asm volatile("v_permlane32_swap_b32 %0, %1" : "+v"(pk[4]), "+v"(pk[6]));
        asm volatile("v_permlane32_swap_b32 %0, %1" : "+v"(pk[5]), "+v"(pk[7]));
        u32x4 fr0 = {pk[0], pk[1], pk[2], pk[3]};
        u32x4 fr1 = {pk[4], pk[5], pk[6], pk[7]};
        f16x8 P0 = __builtin_bit_cast(f16x8, fr0);
        f16x8 P1 = __builtin_bit_cast(f16x8, fr1);

        // ---- PV ----
        __builtin_amdgcn_s_setprio(1);
#pragma unroll
        for (int vt = 0; vt < 2; ++vt) acc[vt] = MFMA32(Vf[0][vt], P0, acc[vt]);
#pragma unroll
        for (int vt = 0; vt < 2; ++vt) acc[vt] = MFMA32(Vf[1][vt], P1, acc[vt]);
        __builtin_amdgcn_s_setprio(0);
    }

    // ---- epilogue: normalize, store frag-native o2 ----
    // element (q = q0+lq, v = vb + vt*32 + 8*rq + 4*hi + j):
    //   ltile = q>>4, ks = v>>5 = vq*2+vt, lane' = rq*16 + (q&15), elem = 4hi+j
    const float inv = 1.f / l_run;
    const int qtile = (q0 >> 4) + (lq >> 4);
    const int ql    = lq & 15;
#pragma unroll
    for (int vt = 0; vt < 2; ++vt)
#pragma unroll
        for (int rq = 0; rq < 4; ++rq) {
            f16x4 o;
#pragma unroll
            for (int j = 0; j < 4; ++j) o[j] = (f16)(acc[vt][4 * rq + j] * inv);
            f16* p = o2 + ((((size_t)b * 256 + qtile) * 8 + vq * 2 + vt) * 64 +
                           rq * 16 + ql) * 8 + 4 * hi;
            *reinterpret_cast<f16x4*>(p) = o;
        }
}

// ---------------------------------------------------------------------------
// Kernel C: MFMA output projection + residual.
//   r8 orientation (mfma(Wo, o_in): D row = oc, col = l -> coalesced scalar
//   stores), both fragment loads now from frag-native layouts (WoF, o2):
//   1KB-contiguous wave-loads instead of 64-line scatters.
// ---------------------------------------------------------------------------
__global__ __launch_bounds__(256) void out_mfma(const f16* __restrict__ WoF,
                                                const f16* __restrict__ o2,
                                                const float* __restrict__ x,
                                                const float* __restrict__ gamma_p,
                                                float* __restrict__ out) {
    const int b    = blockIdx.z;
    const int l0   = blockIdx.x * 64;
    const int wid  = threadIdx.x >> 6;
    const int oc0  = blockIdx.y * 64 + wid * 16;
    const int lane = threadIdx.x & 63;
    const int lq   = lane & 15;
    const int g    = lane >> 4;

    f32x4 acc[4] = {{0.f, 0.f, 0.f, 0.f}, {0.f, 0.f, 0.f, 0.f},
                    {0.f, 0.f, 0.f, 0.f}, {0.f, 0.f, 0.f, 0.f}};
#pragma unroll
    for (int ks = 0; ks < 8; ++ks) {
        f16x8 A = *reinterpret_cast<const f16x8*>(
            WoF + (((size_t)(oc0 >> 4) * 8 + ks) * 64 + lane) * 8);
#pragma unroll
        for (int lt = 0; lt < 4; ++lt) {
            const f16* bp = o2 + (((size_t)(b * 256 + (l0 >> 4) + lt) * 8 + ks) * 64 +
                                  lane) * 8;
            acc[lt] = MFMA16(A, *reinterpret_cast<const f16x8*>(bp), acc[lt]);
        }
    }
    const float gamma = *gamma_p;
#pragma unroll
    for (int lt = 0; lt < 4; ++lt)
#pragma unroll
        for (int r = 0; r < 4; ++r) {
            const size_t o = ((size_t)b * C_ + oc0 + 4 * g + r) * L_ + l0 + lt * 16 + lq;
            out[o] = fmaf(gamma, acc[lt][r], x[o]);
        }
}

// ---------------------------------------------------------------------------
extern "C" void kernel_launch(void* const* d_in, const int* in_sizes, int n_in,
                              void* d_out, int out_size, void* d_ws, size_t ws_size,
                              hipStream_t stream) {
    const float* x       = (const float*)d_in[0];
    const float* W_theta = (const float*)d_in[1];
    const float* W_phi   = (const float*)d_in[2];
    const float* W_g     = (const float*)d_in[3];
    const float* W_o     = (const float*)d_in[4];
    const float* gamma   = (const float*)d_in[5];
    float* out = (float*)d_out;

    // workspace carve (f16): theta2 | phi2 | g2 | o2 | WoF | WallF
    f16* theta2 = (f16*)d_ws;                          // [B][8][L][8]
    f16* phi2   = theta2 + (size_t)B_ * 8 * L_ * 8;    // [B][8][M][8]
    f16* g2     = phi2 + (size_t)B_ * 8 * M_ * 8;      // [B][256][CV][8]
    f16* o2     = g2 + (size_t)B_ * 256 * CV_ * 8;     // [B][256][8][64][8]
    f16* WoF    = o2 + (size_t)B_ * L_ * CV_;          // [32][8][64][8]
    f16* WallF  = WoF + (size_t)C_ * CV_;              // [24][16][64][8]

    const int cvt_n = 384 * 512 + 512 * 256;  // 327680
    cvt_all<<<dim3(cvt_n / 256), 256, 0, stream>>>(W_theta, W_phi, W_g, W_o, WallF, WoF);
    fused_proj<<<dim3(L_ / 32, B_), 256, 0, stream>>>(WallF, x, theta2, phi2, g2);
    attn_flash<<<dim3(512), 512, 0, stream>>>(theta2, phi2, g2, o2);
    out_mfma<<<dim3(L_ / 64, C_ / 64, B_), 256, 0, stream>>>(WoF, o2, x, gamma, out);
}

// Round 12
// 176.918 us; speedup vs baseline: 1.3978x; 1.0022x over previous
//
#include <hip/hip_runtime.h>
#include <cstdint>
#include <cstddef>

// Problem constants
#define B_ 8
#define C_ 512
#define L_ 4096
#define M_ 2048   // L/2 (pooled keys)
#define CK_ 64    // C/8
#define CV_ 256   // C/2

typedef _Float16 f16;
typedef _Float16 f16x8 __attribute__((ext_vector_type(8)));
typedef _Float16 f16x4 __attribute__((ext_vector_type(4)));
typedef float f32x4 __attribute__((ext_vector_type(4)));
typedef float f32x16 __attribute__((ext_vector_type(16)));
typedef unsigned int u32x4 __attribute__((ext_vector_type(4)));

#define MFMA16(A, Bv, Cv) __builtin_amdgcn_mfma_f32_16x16x32_f16(A, Bv, Cv, 0, 0, 0)
#define MFMA32(A, Bv, Cv) __builtin_amdgcn_mfma_f32_32x32x16_f16(A, Bv, Cv, 0, 0, 0)

#define LOG2E 1.44269504f

static __device__ __forceinline__ uint32_t pkrtz(float a, float b) {
    return __builtin_bit_cast(uint32_t, __builtin_amdgcn_cvt_pkrtz(a, b));
}

// ---------------------------------------------------------------------------
// Kernel W: weight conversion into FRAGMENT-NATIVE layouts. (r11-verified)
// ---------------------------------------------------------------------------
__global__ __launch_bounds__(256) void cvt_all(const float* __restrict__ Wt,
                                               const float* __restrict__ Wp,
                                               const float* __restrict__ Wg,
                                               const float* __restrict__ Wo,
                                               f16* __restrict__ WallF,
                                               f16* __restrict__ WoF) {
    const int i = blockIdx.x * 256 + threadIdx.x;
    const int NW = 384 * 512;  // 196608
    if (i < NW) {
        const int och = i >> 9, c = i & 511;
        float v;
        if (och < 64)       v = Wt[i];
        else if (och < 128) v = Wp[i - 64 * 512];
        else                v = Wg[i - 128 * 512];
        const int idx = (((och >> 4) * 16 + (c >> 5)) * 64 +
                         (((c >> 3) & 3) << 4) + (och & 15)) * 8 + (c & 7);
        WallF[idx] = (f16)v;
    } else {
        const int j = i - NW;  // < 131072
        const int oc = j >> 8, v = j & 255;
        const int idx = (((oc >> 4) * 8 + (v >> 5)) * 64 +
                         (((v >> 3) & 3) << 4) + (oc & 15)) * 8 + (v & 7);
        WoF[idx] = (f16)Wo[j];
    }
}

// ---------------------------------------------------------------------------
// Fused projection kernel (MFMA f16, fp32 accum), x staged via LDS.
//   (r11-verified, unchanged)
// ---------------------------------------------------------------------------
__global__ __launch_bounds__(256) void fused_proj(const f16* __restrict__ WallF,
                                                  const float* __restrict__ x,
                                                  f16* __restrict__ theta2,
                                                  f16* __restrict__ phi2,
                                                  f16* __restrict__ g2) {
    __shared__ __align__(16) f16 xs[64][32][8];  // 32 KB
    const int b    = blockIdx.y;
    const int l0   = blockIdx.x * 32;
    const int tid  = threadIdx.x;
    const int w    = tid >> 6;           // warp: och range [w*96, w*96+96)
    const int lane = tid & 63;
    const int lq   = lane & 15;
    const int g    = lane >> 4;
    const int wb   = w * 96;

    // ---- stage x tile -> LDS (f16, fragment-native) ----
    {
        const float* xb = x + (size_t)b * C_ * L_ + l0 + (tid & 31);
        const int co0 = tid >> 5;  // 0..7
#pragma unroll
        for (int i = 0; i < 8; ++i) {
            const int co = i * 8 + co0;
            float v[8];
#pragma unroll
            for (int j = 0; j < 8; ++j) v[j] = xb[(size_t)(co * 8 + j) * L_];
            u32x4 p = {pkrtz(v[0], v[1]), pkrtz(v[2], v[3]),
                       pkrtz(v[4], v[5]), pkrtz(v[6], v[7])};
            *reinterpret_cast<u32x4*>(&xs[co][tid & 31][0]) = p;
        }
    }
    __syncthreads();

    f32x4 acc[6][2] = {};
    for (int ks = 0; ks < 16; ++ks) {
        f16x8 Bf[2];
#pragma unroll
        for (int lt = 0; lt < 2; ++lt)
            Bf[lt] = *reinterpret_cast<const f16x8*>(&xs[ks * 4 + g][lt * 16 + lq][0]);
#pragma unroll
        for (int t = 0; t < 6; ++t) {
            f16x8 Af = *reinterpret_cast<const f16x8*>(
                WallF + (((size_t)(6 * w + t) * 16 + ks) * 64 + lane) * 8);
            acc[t][0] = MFMA16(Af, Bf[0], acc[t][0]);
            acc[t][1] = MFMA16(Af, Bf[1], acc[t][1]);
        }
    }

    // Epilogue. D layout (MFMA16): row = 4g + r (och), col = lq (l).
#pragma unroll
    for (int t = 0; t < 6; ++t) {
        const int och0 = wb + t * 16;
#pragma unroll
        for (int lt = 0; lt < 2; ++lt) {
            const int l = l0 + lt * 16 + lq;
            if (och0 < 64) {
#pragma unroll
                for (int r = 0; r < 4; ++r) {
                    const int och = och0 + 4 * g + r;
                    theta2[(((size_t)b * 8 + (och >> 3)) * L_ + l) * 8 + (och & 7)] =
                        (f16)(acc[t][lt][r] * LOG2E);
                }
            } else {
#pragma unroll
                for (int r = 0; r < 4; ++r) {
                    const float pv = fmaxf(acc[t][lt][r], __shfl_xor(acc[t][lt][r], 1));
                    if (!(lane & 1)) {
                        const int m = l >> 1;
                        if (och0 < 128) {
                            const int kc = och0 - 64 + 4 * g + r;
                            phi2[(((size_t)b * 8 + (kc >> 3)) * M_ + m) * 8 + (kc & 7)] =
                                (f16)pv;
                        } else {
                            const int vc = och0 - 128 + 4 * g + r;
                            g2[(((size_t)b * 256 + (m >> 3)) * CV_ + vc) * 8 + (m & 7)] =
                                (f16)pv;
                        }
                    }
                }
            }
        }
    }
}

// ---------------------------------------------------------------------------
// Kernel B: flash attention, zero LDS / zero barriers.
//   r8/r11 loop structure; this round strength-reduces addressing to
//   SGPR-base + 32-bit offsets (+const per step), defers the l_run
//   cross-half shfl to the epilogue (lane pairs share m_run -> identical
//   rescale factors, so deferral is exact), and makes the defer-max branch
//   wave-uniform via __any with m_new = max(m_run, tm) (exp2(0)=1 exact
//   for non-triggering lanes). NO register prefetch (failed r6/r9).
// ---------------------------------------------------------------------------
__global__ __launch_bounds__(512, 4) void attn_flash(const f16* __restrict__ theta2,
                                                     const f16* __restrict__ phi2,
                                                     const f16* __restrict__ g2,
                                                     f16* __restrict__ o2) {
    const int bid = blockIdx.x;
    const int b   = bid & 7;            // XCD-major: one batch per XCD
    const int qt  = bid >> 3;           // 64 q-tiles (of 64) per batch
    const int w   = threadIdx.x >> 6;   // 0..7
    const int qg  = w >> 2;             // 0..1
    const int vq  = w & 3;              // 0..3
    const int q0  = qt * 64 + qg * 32;
    const int vb  = vq * 64;
    const int lane = threadIdx.x & 63;
    const int lq   = lane & 31;
    const int hi   = lane >> 5;

    const f16* qbase = theta2 + (size_t)b * 8 * L_ * 8;
    f16x8 Qf[4];
#pragma unroll
    for (int f = 0; f < 4; ++f)
        Qf[f] = *reinterpret_cast<const f16x8*>(
            qbase + ((size_t)(2 * f + hi) * L_ + q0 + lq) * 8);

    f32x16 acc[2] = {};
    float m_run = -3.0e38f;
    float l_run = 0.f;

    const f16* kbase = phi2 + (size_t)b * 8 * M_ * 8;
    const f16* vbase = g2 + (size_t)b * 256 * CV_ * 8;

    // 32-bit element offsets, incremented by constants per step.
    uint32_t ko[4], vo[4];
#pragma unroll
    for (int f = 0; f < 4; ++f) ko[f] = ((2 * f + hi) * M_ + lq) * 8u;
#pragma unroll
    for (int ch = 0; ch < 2; ++ch)
#pragma unroll
        for (int vt = 0; vt < 2; ++vt)
            vo[ch * 2 + vt] = ((2 * ch + hi) * CV_ + vb + vt * 32 + lq) * 8u;

    for (int m0 = 0; m0 < M_; m0 += 32) {
        // ---- loads: saddr + 32-bit voffset, no per-step mul chains ----
        f16x8 Kf[4];
#pragma unroll
        for (int f = 0; f < 4; ++f)
            Kf[f] = *reinterpret_cast<const f16x8*>(kbase + ko[f]);
        f16x8 Vf[2][2];
#pragma unroll
        for (int ch = 0; ch < 2; ++ch)
#pragma unroll
            for (int vt = 0; vt < 2; ++vt)
                Vf[ch][vt] = *reinterpret_cast<const f16x8*>(vbase + vo[ch * 2 + vt]);

        // ---- QK^T (scores in log2 units): S^T[m][q], col = q ----
        f32x16 S = {};
        __builtin_amdgcn_s_setprio(1);
#pragma unroll
        for (int f = 0; f < 4; ++f) S = MFMA32(Kf[f], Qf[f], S);
        __builtin_amdgcn_s_setprio(0);

        // ---- online softmax, exp2 domain (per-lane; q is lane-local) ----
        float t0 = fmaxf(fmaxf(S[0], S[1]), S[2]);
        float t1 = fmaxf(fmaxf(S[3], S[4]), S[5]);
        float t2 = fmaxf(fmaxf(S[6], S[7]), S[8]);
        float t3 = fmaxf(fmaxf(S[9], S[10]), S[11]);
        float t4 = fmaxf(fmaxf(S[12], S[13]), S[14]);
        float tm = fmaxf(fmaxf(fmaxf(t0, t1), t2),
                         fmaxf(fmaxf(t3, t4), S[15]));
        tm = fmaxf(tm, __shfl_xor(tm, 32));
        if (__any(tm > m_run + 11.5f)) {  // wave-uniform defer-max
            const float m_new = fmaxf(m_run, tm);
            const float sc = __builtin_amdgcn_exp2f(m_run - m_new);  // =1 if no growth
#pragma unroll
            for (int vt = 0; vt < 2; ++vt)
#pragma unroll
                for (int r = 0; r < 16; ++r) acc[vt][r] *= sc;
            l_run *= sc;
            m_run = m_new;
        }
        float s[16];
#pragma unroll
        for (int r = 0; r < 16; ++r) s[r] = __builtin_amdgcn_exp2f(S[r] - m_run);
        float a0 = (s[0] + s[1]) + (s[2] + s[3]);
        float a1 = (s[4] + s[5]) + (s[6] + s[7]);
        float a2 = (s[8] + s[9]) + (s[10] + s[11]);
        float a3 = (s[12] + s[13]) + (s[14] + s[15]);
        l_run += (a0 + a1) + (a2 + a3);  // per-lane-half; merged in epilogue

        // ---- P -> f16 B-fragments (cvt_pkrtz + permlane32_swap, T12) ----
        uint32_t pk[8];
#pragma unroll
        for (int i = 0; i < 8; ++i) pk[i] = pkrtz(s[2 * i], s[2 * i + 1]);
        asm volatile("v_permlane32_swap_b32 %0, %1" : "+v"(pk[0]), "+v"(pk[2]));
        asm volatile("v_permlane32_swap_b32 %0, %1" : "+v"(pk[1]), "+v"(pk[3]));
        asm volatile("v_permlane32_swap_b32 %0, %1" : "+v"(pk[4]), "+v"(pk[6]));
        asm volatile("v_permlane32_swap_b32 %0, %1" : "+v"(pk[5]), "+v"(pk[7]));
        u32x4 fr0 = {pk[0], pk[1], pk[2], pk[3]};
        u32x4 fr1 = {pk[4], pk[5], pk[6], pk[7]};
        f16x8 P0 = __builtin_bit_cast(f16x8, fr0);
        f16x8 P1 = __builtin_bit_cast(f16x8, fr1);

        // ---- PV ----
        __builtin_amdgcn_s_setprio(1);
#pragma unroll
        for (int vt = 0; vt < 2; ++vt) acc[vt] = MFMA32(Vf[0][vt], P0, acc[vt]);
#pragma unroll
        for (int vt = 0; vt < 2; ++vt) acc[vt] = MFMA32(Vf[1][vt], P1, acc[vt]);
        __builtin_amdgcn_s_setprio(0);

        // ---- advance offsets (uniform constants) ----
#pragma unroll
        for (int f = 0; f < 4; ++f) ko[f] += 32u * 8u;        // +32 m
#pragma unroll
        for (int i = 0; i < 4; ++i) vo[i] += 4u * CV_ * 8u;   // +4 m-octets
    }

    // ---- epilogue: merge per-half l_run, normalize, store frag-native o2 ----
    l_run += __shfl_xor(l_run, 32);
    const float inv = 1.f / l_run;
    const int qtile = (q0 >> 4) + (lq >> 4);
    const int ql    = lq & 15;
#pragma unroll
    for (int vt = 0; vt < 2; ++vt)
#pragma unroll
        for (int rq = 0; rq < 4; ++rq) {
            f16x4 o;
#pragma unroll
            for (int j = 0; j < 4; ++j) o[j] = (f16)(acc[vt][4 * rq + j] * inv);
            f16* p = o2 + ((((size_t)b * 256 + qtile) * 8 + vq * 2 + vt) * 64 +
                           rq * 16 + ql) * 8 + 4 * hi;
            *reinterpret_cast<f16x4*>(p) = o;
        }
}

// ---------------------------------------------------------------------------
// Kernel C: MFMA output projection + residual. (r11-verified, unchanged)
// ---------------------------------------------------------------------------
__global__ __launch_bounds__(256) void out_mfma(const f16* __restrict__ WoF,
                                                const f16* __restrict__ o2,
                                                const float* __restrict__ x,
                                                const float* __restrict__ gamma_p,
                                                float* __restrict__ out) {
    const int b    = blockIdx.z;
    const int l0   = blockIdx.x * 64;
    const int wid  = threadIdx.x >> 6;
    const int oc0  = blockIdx.y * 64 + wid * 16;
    const int lane = threadIdx.x & 63;
    const int lq   = lane & 15;
    const int g    = lane >> 4;

    f32x4 acc[4] = {{0.f, 0.f, 0.f, 0.f}, {0.f, 0.f, 0.f, 0.f},
                    {0.f, 0.f, 0.f, 0.f}, {0.f, 0.f, 0.f, 0.f}};
#pragma unroll
    for (int ks = 0; ks < 8; ++ks) {
        f16x8 A = *reinterpret_cast<const f16x8*>(
            WoF + (((size_t)(oc0 >> 4) * 8 + ks) * 64 + lane) * 8);
#pragma unroll
        for (int lt = 0; lt < 4; ++lt) {
            const f16* bp = o2 + (((size_t)(b * 256 + (l0 >> 4) + lt) * 8 + ks) * 64 +
                                  lane) * 8;
            acc[lt] = MFMA16(A, *reinterpret_cast<const f16x8*>(bp), acc[lt]);
        }
    }
    const float gamma = *gamma_p;
#pragma unroll
    for (int lt = 0; lt < 4; ++lt)
#pragma unroll
        for (int r = 0; r < 4; ++r) {
            const size_t o = ((size_t)b * C_ + oc0 + 4 * g + r) * L_ + l0 + lt * 16 + lq;
            out[o] = fmaf(gamma, acc[lt][r], x[o]);
        }
}

// ---------------------------------------------------------------------------
extern "C" void kernel_launch(void* const* d_in, const int* in_sizes, int n_in,
                              void* d_out, int out_size, void* d_ws, size_t ws_size,
                              hipStream_t stream) {
    const float* x       = (const float*)d_in[0];
    const float* W_theta = (const float*)d_in[1];
    const float* W_phi   = (const float*)d_in[2];
    const float* W_g     = (const float*)d_in[3];
    const float* W_o     = (const float*)d_in[4];
    const float* gamma   = (const float*)d_in[5];
    float* out = (float*)d_out;

    // workspace carve (f16): theta2 | phi2 | g2 | o2 | WoF | WallF
    f16* theta2 = (f16*)d_ws;                          // [B][8][L][8]
    f16* phi2   = theta2 + (size_t)B_ * 8 * L_ * 8;    // [B][8][M][8]
    f16* g2     = phi2 + (size_t)B_ * 8 * M_ * 8;      // [B][256][CV][8]
    f16* o2     = g2 + (size_t)B_ * 256 * CV_ * 8;     // [B][256][8][64][8]
    f16* WoF    = o2 + (size_t)B_ * L_ * CV_;          // [32][8][64][8]
    f16* WallF  = WoF + (size_t)C_ * CV_;              // [24][16][64][8]

    const int cvt_n = 384 * 512 + 512 * 256;  // 327680
    cvt_all<<<dim3(cvt_n / 256), 256, 0, stream>>>(W_theta, W_phi, W_g, W_o, WallF, WoF);
    fused_proj<<<dim3(L_ / 32, B_), 256, 0, stream>>>(WallF, x, theta2, phi2, g2);
    attn_flash<<<dim3(512), 512, 0, stream>>>(theta2, phi2, g2, o2);
    out_mfma<<<dim3(L_ / 64, C_ / 64, B_), 256, 0, stream>>>(WoF, o2, x, gamma, out);
}